// Round 5
// baseline (2110.761 us; speedup 1.0000x reference)
//
#include <hip/hip_runtime.h>

#define NP 4096          // number of points (fixed by problem)
#define NJC 16           // j-chunks for the main conv
#define JCH (NP / NJC)   // 256 j's per conv workgroup
#define HTS 260          // sHT row stride (floats): 16B-aligned, good bank spread

typedef const float* fp;

using half8  = __attribute__((ext_vector_type(8)))  _Float16;
using f32x16 = __attribute__((ext_vector_type(16))) float;

__device__ __forceinline__ float lk(float x) { return x >= 0.f ? x : 0.2f * x; }

// ---- workspace layout (float offsets) ----
// zeroed region (memset each launch):
#define OFF_ACC   0                       // [0..7] gsum/gssq in, [8..15] gsum/gssq out
#define OFF_OV    16                      // 2*NP  load_mesh ov accumulator
#define OFF_CONV  (16 + 2*NP)             // 16*NP conv output accumulator
#define ZERO_FLTS (16 + 2*NP + 16*NP)
// plain scratch:
#define OFF_SC    ZERO_FLTS               // NP     scores
#define OFF_UV    (OFF_SC  + NP)          // 6*NP   tangent vectors u,v
#define OFF_P9    (OFF_UV  + 6*NP)        // 3*NP   xyz / RADIUS
#define OFF_NRM   (OFF_P9  + 3*NP)        // 3*NP   normals fp32
#define OFF_HPRE  (OFF_NRM + 3*NP)        // 16*NP  h before group_norm
#define OFF_HNRM  (OFF_HPRE+ 16*NP)       // 16*NP  h after group_norm (16B-aligned)
#define OFF_NUV   (OFF_HNRM+ 16*NP)       // 9*NP   nuv frames
#define OFF_Y2    (OFF_NUV + 9*NP)        // 16*NP  y after output MLP (pre group_norm)
#define WS_FLTS   (OFF_Y2  + 16*NP)

// ---------------- K1: per-point prep ----------------
__global__ __launch_bounds__(256) void k_prep(
    fp xyz, fp nrm, fp feats,
    fp osw1, fp osb1, fp osw2, fp osb2,
    fp niw1, fp nib1, fp niw2, fp nib2,
    float* __restrict__ ws)
{
    const int i = blockIdx.x * 256 + threadIdx.x;

    float f[16];
#pragma unroll
    for (int c = 0; c < 16; c++) f[c] = feats[i * 16 + c];

    float sc = osb2[0];
#pragma unroll
    for (int u = 0; u < 16; u++) {
        float a = osb1[u];
#pragma unroll
        for (int c = 0; c < 16; c++) a += osw1[u * 16 + c] * f[c];
        sc += osw2[u] * lk(a);
    }
    ws[OFF_SC + i] = sc;

    float h1[16];
#pragma unroll
    for (int u = 0; u < 16; u++) {
        float a = nib1[u];
#pragma unroll
        for (int c = 0; c < 16; c++) a += niw1[u * 16 + c] * f[c];
        h1[u] = lk(a);
    }
    float h2[16];
#pragma unroll
    for (int u = 0; u < 16; u++) {
        float a = nib2[u];
#pragma unroll
        for (int c = 0; c < 16; c++) a += niw2[u * 16 + c] * h1[c];
        h2[u] = lk(a);
        ws[OFF_HPRE + i * 16 + u] = h2[u];
    }

#pragma unroll
    for (int g = 0; g < 4; g++) {
        float s = 0.f, ss = 0.f;
#pragma unroll
        for (int k = 0; k < 4; k++) { float v = h2[g * 4 + k]; s += v; ss += v * v; }
#pragma unroll
        for (int off = 32; off > 0; off >>= 1) {
            s  += __shfl_down(s,  off);
            ss += __shfl_down(ss, off);
        }
        if ((threadIdx.x & 63) == 0) {
            atomicAdd(&ws[OFF_ACC + g],     s);
            atomicAdd(&ws[OFF_ACC + 4 + g], ss);
        }
    }

    float nx = nrm[i * 3], ny = nrm[i * 3 + 1], nz = nrm[i * 3 + 2];
    float s  = (nz >= 0.f) ? 1.f : -1.f;
    float a  = -1.f / (s + nz);
    float b  = nx * ny * a;
    float ux = 1.f + s * nx * nx * a, uy = s * b,            uz = -s * nx;
    float vx = b,                     vy = s + ny * ny * a,  vz = -ny;
    ws[OFF_UV + i * 6 + 0] = ux; ws[OFF_UV + i * 6 + 1] = uy; ws[OFF_UV + i * 6 + 2] = uz;
    ws[OFF_UV + i * 6 + 3] = vx; ws[OFF_UV + i * 6 + 4] = vy; ws[OFF_UV + i * 6 + 5] = vz;
    const float IR = 1.f / 9.f;
    ws[OFF_P9 + i * 3 + 0] = xyz[i * 3 + 0] * IR;
    ws[OFF_P9 + i * 3 + 1] = xyz[i * 3 + 1] * IR;
    ws[OFF_P9 + i * 3 + 2] = xyz[i * 3 + 2] * IR;
    ws[OFF_NRM + i * 3 + 0] = nx;
    ws[OFF_NRM + i * 3 + 1] = ny;
    ws[OFF_NRM + i * 3 + 2] = nz;
}

// ---------------- K2: load_mesh O(N^2) pair sum ----------------
__global__ __launch_bounds__(256) void k_mesh(float* __restrict__ ws)
{
    __shared__ float sp[3][512];
    __shared__ float sn[3][512];
    __shared__ float ssc[512];
    __shared__ float red[256][2];

    const int tid = threadIdx.x;
    const int ib = blockIdx.x >> 3, jc = blockIdx.x & 7;
    const int il = tid & 63, sub = tid >> 6;
    const int i = ib * 64 + il;
    const int j0 = jc * 512;

    for (int t = tid; t < 512; t += 256) {
        int j = j0 + t;
        sp[0][t] = ws[OFF_P9 + j * 3];     sp[1][t] = ws[OFF_P9 + j * 3 + 1];  sp[2][t] = ws[OFF_P9 + j * 3 + 2];
        sn[0][t] = ws[OFF_NRM + j * 3];    sn[1][t] = ws[OFF_NRM + j * 3 + 1]; sn[2][t] = ws[OFF_NRM + j * 3 + 2];
        ssc[t]   = ws[OFF_SC + j];
    }
    __syncthreads();

    const float pix = ws[OFF_P9 + i * 3], piy = ws[OFF_P9 + i * 3 + 1], piz = ws[OFF_P9 + i * 3 + 2];
    const float nix = ws[OFF_NRM + i * 3], niy = ws[OFF_NRM + i * 3 + 1], niz = ws[OFF_NRM + i * 3 + 2];
    const float ux = ws[OFF_UV + i * 6],     uy = ws[OFF_UV + i * 6 + 1], uz = ws[OFF_UV + i * 6 + 2];
    const float vx = ws[OFF_UV + i * 6 + 3], vy = ws[OFF_UV + i * 6 + 4], vz = ws[OFF_UV + i * 6 + 5];

    float ov0 = 0.f, ov1 = 0.f;
#pragma unroll 4
    for (int t = 0; t < 128; t++) {
        int j = sub * 128 + t;
        float dx = sp[0][j] - pix, dy = sp[1][j] - piy, dz = sp[2][j] - piz;
        float d2 = dx * dx + dy * dy + dz * dz;
        float cs = nix * sn[0][j] + niy * sn[1][j] + niz * sn[2][j];
        float tt = 2.f - cs;
        float w  = __expf(-d2 * tt * tt) * ssc[j];
        ov0 += w * (ux * dx + uy * dy + uz * dz);
        ov1 += w * (vx * dx + vy * dy + vz * dz);
    }
    red[tid][0] = ov0; red[tid][1] = ov1;
    __syncthreads();
    if (sub == 0) {
        float a = ov0 + red[64 + il][0] + red[128 + il][0] + red[192 + il][0];
        float b = ov1 + red[64 + il][1] + red[128 + il][1] + red[192 + il][1];
        atomicAdd(&ws[OFF_OV + i * 2],     a);
        atomicAdd(&ws[OFF_OV + i * 2 + 1], b);
    }
}

// ---------------- K3: finalize nuv + group_norm(h) ----------------
__global__ __launch_bounds__(256) void k_fin(float* __restrict__ ws, fp gng, fp gnb)
{
    const int i = blockIdx.x * 256 + threadIdx.x;

    float o0 = ws[OFF_OV + i * 2]     + 1e-5f;
    float o1 = ws[OFF_OV + i * 2 + 1] + 1e-5f;
    float nr = fmaxf(sqrtf(o0 * o0 + o1 * o1), 1e-12f);
    float ex = o0 / nr, ey = o1 / nr;

    const float ux = ws[OFF_UV + i * 6],     uy = ws[OFF_UV + i * 6 + 1], uz = ws[OFF_UV + i * 6 + 2];
    const float vx = ws[OFF_UV + i * 6 + 3], vy = ws[OFF_UV + i * 6 + 4], vz = ws[OFF_UV + i * 6 + 5];
    const float nx = ws[OFF_NRM + i * 3], ny = ws[OFF_NRM + i * 3 + 1], nz = ws[OFF_NRM + i * 3 + 2];

    ws[OFF_NUV + i * 9 + 0] = nx;
    ws[OFF_NUV + i * 9 + 1] = ny;
    ws[OFF_NUV + i * 9 + 2] = nz;
    ws[OFF_NUV + i * 9 + 3] =  ex * ux + ey * vx;
    ws[OFF_NUV + i * 9 + 4] =  ex * uy + ey * vy;
    ws[OFF_NUV + i * 9 + 5] =  ex * uz + ey * vz;
    ws[OFF_NUV + i * 9 + 6] = -ey * ux + ex * vx;
    ws[OFF_NUV + i * 9 + 7] = -ey * uy + ex * vy;
    ws[OFF_NUV + i * 9 + 8] = -ey * uz + ex * vz;

    const float invM = 1.f / (4.f * NP);
#pragma unroll
    for (int c = 0; c < 16; c++) {
        int g = c >> 2;
        float m   = ws[OFF_ACC + g] * invM;
        float var = ws[OFF_ACC + 4 + g] * invM - m * m;
        float inv = rsqrtf(var + 1e-5f);
        ws[OFF_HNRM + i * 16 + c] =
            (ws[OFF_HPRE + i * 16 + c] - m) * inv * gng[c] + gnb[c];
    }
}

// ---------------- K4: main conv — 32x32x16 MFMA, w folded into A ----------------
// grid = 64 i-blocks x 16 j-chunks, 4 waves; wave handles 16 i's.
// Per (i, 64-j group): geometry+g per lane (lane = local j). w>0 so
// w*relu(A2 g + b2) = relu(A2 (w g) + w b2): A-frag rows m = pairs carry w*g
// (k=0..7) and w itself in the bias K-slot k=8; B-frags carry A2 columns and
// b2 at k=8. Two 32-pair tiles per group; 8 MFMAs each (t packed 2/frag:
// col n: o=n&15, t=2q+(n>>4)). C layout (verified m74/m101): col=lane&31,
// row=(reg&3)+8*(reg>>2)+4*(lane>>5). Stage-2 = relu + fma against static
// transposed h table in LDS (float4 row-runs, 16-lane broadcasts).
__global__ __launch_bounds__(256, 3) void k_conv(
    const float* __restrict__ ws,
    const float* __restrict__ cva1, const float* __restrict__ cvb1,
    const float* __restrict__ A2,   const float* __restrict__ B2,
    float* __restrict__ conv)
{
    __shared__ float4 sP[JCH];
    __shared__ float4 sN[JCH];
    __shared__ float  sHT[16 * HTS];      // h transposed: sHT[t*HTS + j_local]

    const int tid  = threadIdx.x;
    const int ib   = blockIdx.x >> 4;
    const int jc   = blockIdx.x & 15;
    const int j0   = jc * JCH;
    const int lane = tid & 63;
    const int wv   = tid >> 6;
    const int o    = lane & 15;
    const int tpar = (lane >> 4) & 1;     // t parity column group
    const int half = lane >> 5;           // K-half / row-half
    const float IVS2 = 0.70710678118654752f;

    // stage the j-chunk (one j per thread)
    {
        const int t = tid;
        const int j = j0 + t;
        sP[t] = make_float4(ws[OFF_P9 + j * 3] * IVS2,
                            ws[OFF_P9 + j * 3 + 1] * IVS2,
                            ws[OFF_P9 + j * 3 + 2] * IVS2, 0.f);
        sN[t] = make_float4(ws[OFF_NRM + j * 3],
                            ws[OFF_NRM + j * 3 + 1],
                            ws[OFF_NRM + j * 3 + 2], 0.f);
        const float4* hs = (const float4*)(ws + OFF_HNRM + j * 16);
        float4 h0 = hs[0], h1 = hs[1], h2 = hs[2], h3 = hs[3];
        sHT[ 0 * HTS + t] = h0.x; sHT[ 1 * HTS + t] = h0.y;
        sHT[ 2 * HTS + t] = h0.z; sHT[ 3 * HTS + t] = h0.w;
        sHT[ 4 * HTS + t] = h1.x; sHT[ 5 * HTS + t] = h1.y;
        sHT[ 6 * HTS + t] = h1.z; sHT[ 7 * HTS + t] = h1.w;
        sHT[ 8 * HTS + t] = h2.x; sHT[ 9 * HTS + t] = h2.y;
        sHT[10 * HTS + t] = h2.z; sHT[11 * HTS + t] = h2.w;
        sHT[12 * HTS + t] = h3.x; sHT[13 * HTS + t] = h3.y;
        sHT[14 * HTS + t] = h3.z; sHT[15 * HTS + t] = h3.w;
    }

    const half8 h8z = (half8)(_Float16)0.f;

    // B-frags (8, constant per lane): col n = lane&31 -> (o, t=2q+tpar);
    // K half0 = A2 row, K half1 slot0 = b2.
    half8 Bf[8];
#pragma unroll
    for (int q = 0; q < 8; q++) {
        const int t = 2 * q + tpar;
        half8 v = h8z;
        if (half == 0) {
            const float* row = A2 + (o * 16 + t) * 8;
#pragma unroll
            for (int c = 0; c < 8; c++) v[c] = (_Float16)row[c];
        } else {
            v[0] = (_Float16)B2[o * 16 + t];
        }
        Bf[q] = v;
    }

    float a1[24], b1c[8];
#pragma unroll
    for (int k = 0; k < 24; k++) a1[k] = cva1[k];
#pragma unroll
    for (int k = 0; k < 8; k++)  b1c[k] = cvb1[k];

    __syncthreads();

    const f32x16 zc = {0.f,0.f,0.f,0.f,0.f,0.f,0.f,0.f,
                       0.f,0.f,0.f,0.f,0.f,0.f,0.f,0.f};

#pragma unroll 1
    for (int ii = 0; ii < 16; ii++) {
        const int i = ib * 64 + wv * 16 + ii;     // wave-uniform -> s_loads
        const float pix = ws[OFF_P9 + i * 3 + 0] * IVS2;
        const float piy = ws[OFF_P9 + i * 3 + 1] * IVS2;
        const float piz = ws[OFF_P9 + i * 3 + 2] * IVS2;
        float r[9];
#pragma unroll
        for (int k = 0; k < 9; k++) r[k] = ws[OFF_NUV + i * 9 + k];

        float a0 = 0.f, aa1 = 0.f, a2 = 0.f, a3 = 0.f;

#pragma unroll 1
        for (int jg = 0; jg < 4; jg++) {
            // geometry + g for 64 distinct j's (lane = local j)
            const int jl = jg * 64 + lane;
            const float4 pj = sP[jl];
            const float4 nj = sN[jl];
            const float dx = pj.x - pix, dy = pj.y - piy, dz = pj.z - piz;
            const float d2 = dx * dx + dy * dy + dz * dz;
            const float cs = r[0] * nj.x + r[1] * nj.y + r[2] * nj.z;
            const float tt = 2.f - cs;
            const float wwin = __expf(-d2 * tt * tt);
            const float X0 = r[0] * dx + r[1] * dy + r[2] * dz;
            const float X1 = r[3] * dx + r[4] * dy + r[5] * dz;
            const float X2 = r[6] * dx + r[7] * dy + r[8] * dz;

            // w*g packed to f16 (own pair)
            half8 Ag;
#pragma unroll
            for (int c = 0; c < 8; c++) {
                float g = fmaxf(a1[c * 3] * X0 + a1[c * 3 + 1] * X1 +
                                a1[c * 3 + 2] * X2 + b1c[c], 0.f);
                Ag[c] = (_Float16)(wwin * g);
            }

#pragma unroll
            for (int tile = 0; tile < 2; tile++) {
                half8 Af;
                if (tile == 0) {
                    // rows = j 0..31: half0 lanes use own w*g; half1 lanes
                    // supply K bias slot = w of row (lane&31)
                    float wx = __shfl(wwin, lane & 31, 64);
                    half8 Ab = h8z; Ab[0] = (_Float16)wx;
                    Af = (half == 0) ? Ag : Ab;
                } else {
                    // rows = j 32..63: pull w*g from upper lanes
                    int4 gi;
                    __builtin_memcpy(&gi, &Ag, 16);
                    gi.x = __shfl(gi.x, (lane & 31) + 32, 64);
                    gi.y = __shfl(gi.y, (lane & 31) + 32, 64);
                    gi.z = __shfl(gi.z, (lane & 31) + 32, 64);
                    gi.w = __shfl(gi.w, (lane & 31) + 32, 64);
                    half8 Ag1;
                    __builtin_memcpy(&Ag1, &gi, 16);
                    half8 Ab = h8z; Ab[0] = (_Float16)wwin;   // own w = row's w
                    Af = (half == 0) ? Ag1 : Ab;
                }

                const int tb = jg * 64 + tile * 32;
                const float* hb = sHT + tpar * HTS + tb + 4 * half;

                f32x16 Cc = __builtin_amdgcn_mfma_f32_32x32x16_f16(Af, Bf[0], zc, 0, 0, 0);
#pragma unroll
                for (int q = 0; q < 8; q++) {
                    f32x16 Cn;
                    if (q < 7)
                        Cn = __builtin_amdgcn_mfma_f32_32x32x16_f16(Af, Bf[q + 1], zc, 0, 0, 0);
                    const float* qb = hb + q * (2 * HTS);
                    const float4 q0 = *(const float4*)(qb);
                    const float4 q1 = *(const float4*)(qb + 8);
                    const float4 q2 = *(const float4*)(qb + 16);
                    const float4 q3 = *(const float4*)(qb + 24);
                    a0 += q0.x * fmaxf(Cc[0],  0.f) + q0.y * fmaxf(Cc[1],  0.f)
                        + q0.z * fmaxf(Cc[2],  0.f) + q0.w * fmaxf(Cc[3],  0.f);
                    aa1 += q1.x * fmaxf(Cc[4],  0.f) + q1.y * fmaxf(Cc[5],  0.f)
                        + q1.z * fmaxf(Cc[6],  0.f) + q1.w * fmaxf(Cc[7],  0.f);
                    a2 += q2.x * fmaxf(Cc[8],  0.f) + q2.y * fmaxf(Cc[9],  0.f)
                        + q2.z * fmaxf(Cc[10], 0.f) + q2.w * fmaxf(Cc[11], 0.f);
                    a3 += q3.x * fmaxf(Cc[12], 0.f) + q3.y * fmaxf(Cc[13], 0.f)
                        + q3.z * fmaxf(Cc[14], 0.f) + q3.w * fmaxf(Cc[15], 0.f);
                    Cc = Cn;
                }
            }
        }

        float accO = (a0 + aa1) + (a2 + a3);
        accO += __shfl_xor(accO, 16, 64);
        accO += __shfl_xor(accO, 32, 64);
        if (lane < 16) atomicAdd(&conv[i * 16 + o], accO);
    }
}

// ---------------- K5: output MLP + group sums ----------------
__global__ __launch_bounds__(256) void k_post1(
    float* __restrict__ ws, fp now1, fp nob1, fp now2, fp nob2)
{
    const int i = blockIdx.x * 256 + threadIdx.x;
    float cv[16];
#pragma unroll
    for (int o = 0; o < 16; o++) cv[o] = ws[OFF_CONV + i * 16 + o];

    float y1[16];
#pragma unroll
    for (int u = 0; u < 16; u++) {
        float a = nob1[u];
#pragma unroll
        for (int k = 0; k < 16; k++) a += now1[u * 16 + k] * cv[k];
        y1[u] = lk(a);
    }
    float y2[16];
#pragma unroll
    for (int u = 0; u < 16; u++) {
        float a = nob2[u];
#pragma unroll
        for (int k = 0; k < 16; k++) a += now2[u * 16 + k] * y1[k];
        y2[u] = lk(a);
        ws[OFF_Y2 + i * 16 + u] = y2[u];
    }
#pragma unroll
    for (int g = 0; g < 4; g++) {
        float s = 0.f, ss = 0.f;
#pragma unroll
        for (int k = 0; k < 4; k++) { float v = y2[g * 4 + k]; s += v; ss += v * v; }
#pragma unroll
        for (int off = 32; off > 0; off >>= 1) {
            s  += __shfl_down(s,  off);
            ss += __shfl_down(ss, off);
        }
        if ((threadIdx.x & 63) == 0) {
            atomicAdd(&ws[OFF_ACC + 8 + g],  s);
            atomicAdd(&ws[OFF_ACC + 12 + g], ss);
        }
    }
}

// ---------------- K6: group_norm(y) + site MLP + linear transform + sum ----------------
__global__ __launch_bounds__(256) void k_post2(
    const float* __restrict__ ws, fp feats, fp gg, fp gb,
    fp llw1, fp llb1, fp llw2, fp llb2, fp ltw, fp ltb,
    float* __restrict__ out)
{
    const int i = blockIdx.x * 256 + threadIdx.x;
    const float invM = 1.f / (4.f * NP);

    float z[16];
#pragma unroll
    for (int c = 0; c < 16; c++) {
        int g = c >> 2;
        float m   = ws[OFF_ACC + 8 + g] * invM;
        float var = ws[OFF_ACC + 12 + g] * invM - m * m;
        float inv = rsqrtf(var + 1e-5f);
        z[c] = (ws[OFF_Y2 + i * 16 + c] - m) * inv * gg[c] + gb[c];
    }
    float r1[16];
#pragma unroll
    for (int o = 0; o < 16; o++) {
        float a = llb1[o];
#pragma unroll
        for (int k = 0; k < 16; k++) a += llw1[o * 16 + k] * z[k];
        r1[o] = fmaxf(a, 0.f);
    }
    float f[16];
#pragma unroll
    for (int c = 0; c < 16; c++) f[c] = feats[i * 16 + c];
#pragma unroll
    for (int o = 0; o < 16; o++) {
        float a = llb2[o];
#pragma unroll
        for (int k = 0; k < 16; k++) a += llw2[o * 16 + k] * r1[k];
        float x = ltb[o];
#pragma unroll
        for (int k = 0; k < 16; k++) x += ltw[o * 16 + k] * f[k];
        out[i * 16 + o] = x + a;
    }
}

extern "C" void kernel_launch(void* const* d_in, const int* in_sizes, int n_in,
                              void* d_out, int out_size, void* d_ws, size_t ws_size,
                              hipStream_t stream)
{
    fp xyz  = (fp)d_in[0];
    fp nrm  = (fp)d_in[1];
    fp fts  = (fp)d_in[2];
    fp osw1 = (fp)d_in[3],  osb1 = (fp)d_in[4],  osw2 = (fp)d_in[5],  osb2 = (fp)d_in[6];
    fp niw1 = (fp)d_in[7],  nib1 = (fp)d_in[8],  niw2 = (fp)d_in[9],  nib2 = (fp)d_in[10];
    fp gng  = (fp)d_in[11], gnb  = (fp)d_in[12];
    fp cva1 = (fp)d_in[13], cvb1 = (fp)d_in[14], cva2 = (fp)d_in[15], cvb2 = (fp)d_in[16];
    fp now1 = (fp)d_in[17], nob1 = (fp)d_in[18], now2 = (fp)d_in[19], nob2 = (fp)d_in[20];
    fp gog  = (fp)d_in[21], gob  = (fp)d_in[22];
    fp llw1 = (fp)d_in[23], llb1 = (fp)d_in[24], llw2 = (fp)d_in[25], llb2 = (fp)d_in[26];
    fp ltw  = (fp)d_in[27], ltb  = (fp)d_in[28];

    float* ws = (float*)d_ws;

    hipMemsetAsync(d_ws, 0, (size_t)ZERO_FLTS * sizeof(float), stream);
    k_prep<<<NP / 256, 256, 0, stream>>>(xyz, nrm, fts,
                                         osw1, osb1, osw2, osb2,
                                         niw1, nib1, niw2, nib2, ws);
    k_mesh<<<512, 256, 0, stream>>>(ws);
    k_fin<<<NP / 256, 256, 0, stream>>>(ws, gng, gnb);
    k_conv<<<64 * NJC, 256, 0, stream>>>(ws, cva1, cvb1, cva2, cvb2, ws + OFF_CONV);
    k_post1<<<NP / 256, 256, 0, stream>>>(ws, now1, nob1, now2, nob2);
    k_post2<<<NP / 256, 256, 0, stream>>>(ws, fts, gog, gob,
                                          llw1, llb1, llw2, llb2, ltw, ltb,
                                          (float*)d_out);
}

// Round 7
// 531.081 us; speedup vs baseline: 3.9745x; 3.9745x over previous
//
#include <hip/hip_runtime.h>

#define NP 4096          // number of points (fixed by problem)
#define NJC 16           // j-chunks for the main conv
#define JCH (NP / NJC)   // 256 j's per conv workgroup
#define HR  12           // sH2 row stride in 32-bit words (48B): 16B-aligned, 2-way banks

typedef const float* fp;

using half8  = __attribute__((ext_vector_type(8))) _Float16;   // MFMA frag type
using fp16x2 = __attribute__((ext_vector_type(2))) __fp16;     // pkrtz/fdot2 type
using f32x4  = __attribute__((ext_vector_type(4))) float;

__device__ __forceinline__ float lk(float x) { return x >= 0.f ? x : 0.2f * x; }

__device__ __forceinline__ unsigned int pkrtz(float a, float b) {
    fp16x2 h = __builtin_amdgcn_cvt_pkrtz(a, b);
    unsigned int u; __builtin_memcpy(&u, &h, 4); return u;
}
__device__ __forceinline__ fp16x2 u2h(unsigned int u) {
    fp16x2 h; __builtin_memcpy(&h, &u, 4); return h;
}

// ---- workspace layout (float offsets) ----
// zeroed region (memset each launch):
#define OFF_ACC   0                       // [0..7] gsum/gssq in, [8..15] gsum/gssq out
#define OFF_OV    16                      // 2*NP  load_mesh ov accumulator
#define OFF_CONV  (16 + 2*NP)             // 16*NP conv output accumulator
#define ZERO_FLTS (16 + 2*NP + 16*NP)
// plain scratch:
#define OFF_SC    ZERO_FLTS               // NP     scores
#define OFF_UV    (OFF_SC  + NP)          // 6*NP   tangent vectors u,v
#define OFF_P9    (OFF_UV  + 6*NP)        // 3*NP   xyz / RADIUS
#define OFF_NRM   (OFF_P9  + 3*NP)        // 3*NP   normals fp32
#define OFF_HPRE  (OFF_NRM + 3*NP)        // 16*NP  h before group_norm
#define OFF_HNRM  (OFF_HPRE+ 16*NP)       // 16*NP  h after group_norm (16B-aligned)
#define OFF_NUV   (OFF_HNRM+ 16*NP)       // 9*NP   nuv frames
#define OFF_Y2    (OFF_NUV + 9*NP)        // 16*NP  y after output MLP (pre group_norm)
#define WS_FLTS   (OFF_Y2  + 16*NP)

// ---------------- K1: per-point prep ----------------
__global__ __launch_bounds__(256) void k_prep(
    fp xyz, fp nrm, fp feats,
    fp osw1, fp osb1, fp osw2, fp osb2,
    fp niw1, fp nib1, fp niw2, fp nib2,
    float* __restrict__ ws)
{
    const int i = blockIdx.x * 256 + threadIdx.x;

    float f[16];
#pragma unroll
    for (int c = 0; c < 16; c++) f[c] = feats[i * 16 + c];

    float sc = osb2[0];
#pragma unroll
    for (int u = 0; u < 16; u++) {
        float a = osb1[u];
#pragma unroll
        for (int c = 0; c < 16; c++) a += osw1[u * 16 + c] * f[c];
        sc += osw2[u] * lk(a);
    }
    ws[OFF_SC + i] = sc;

    float h1[16];
#pragma unroll
    for (int u = 0; u < 16; u++) {
        float a = nib1[u];
#pragma unroll
        for (int c = 0; c < 16; c++) a += niw1[u * 16 + c] * f[c];
        h1[u] = lk(a);
    }
    float h2[16];
#pragma unroll
    for (int u = 0; u < 16; u++) {
        float a = nib2[u];
#pragma unroll
        for (int c = 0; c < 16; c++) a += niw2[u * 16 + c] * h1[c];
        h2[u] = lk(a);
        ws[OFF_HPRE + i * 16 + u] = h2[u];
    }

#pragma unroll
    for (int g = 0; g < 4; g++) {
        float s = 0.f, ss = 0.f;
#pragma unroll
        for (int k = 0; k < 4; k++) { float v = h2[g * 4 + k]; s += v; ss += v * v; }
#pragma unroll
        for (int off = 32; off > 0; off >>= 1) {
            s  += __shfl_down(s,  off);
            ss += __shfl_down(ss, off);
        }
        if ((threadIdx.x & 63) == 0) {
            atomicAdd(&ws[OFF_ACC + g],     s);
            atomicAdd(&ws[OFF_ACC + 4 + g], ss);
        }
    }

    float nx = nrm[i * 3], ny = nrm[i * 3 + 1], nz = nrm[i * 3 + 2];
    float s  = (nz >= 0.f) ? 1.f : -1.f;
    float a  = -1.f / (s + nz);
    float b  = nx * ny * a;
    float ux = 1.f + s * nx * nx * a, uy = s * b,            uz = -s * nx;
    float vx = b,                     vy = s + ny * ny * a,  vz = -ny;
    ws[OFF_UV + i * 6 + 0] = ux; ws[OFF_UV + i * 6 + 1] = uy; ws[OFF_UV + i * 6 + 2] = uz;
    ws[OFF_UV + i * 6 + 3] = vx; ws[OFF_UV + i * 6 + 4] = vy; ws[OFF_UV + i * 6 + 5] = vz;
    const float IR = 1.f / 9.f;
    ws[OFF_P9 + i * 3 + 0] = xyz[i * 3 + 0] * IR;
    ws[OFF_P9 + i * 3 + 1] = xyz[i * 3 + 1] * IR;
    ws[OFF_P9 + i * 3 + 2] = xyz[i * 3 + 2] * IR;
    ws[OFF_NRM + i * 3 + 0] = nx;
    ws[OFF_NRM + i * 3 + 1] = ny;
    ws[OFF_NRM + i * 3 + 2] = nz;
}

// ---------------- K2: load_mesh O(N^2) pair sum ----------------
__global__ __launch_bounds__(256) void k_mesh(float* __restrict__ ws)
{
    __shared__ float sp[3][512];
    __shared__ float sn[3][512];
    __shared__ float ssc[512];
    __shared__ float red[256][2];

    const int tid = threadIdx.x;
    const int ib = blockIdx.x >> 3, jc = blockIdx.x & 7;
    const int il = tid & 63, sub = tid >> 6;
    const int i = ib * 64 + il;
    const int j0 = jc * 512;

    for (int t = tid; t < 512; t += 256) {
        int j = j0 + t;
        sp[0][t] = ws[OFF_P9 + j * 3];     sp[1][t] = ws[OFF_P9 + j * 3 + 1];  sp[2][t] = ws[OFF_P9 + j * 3 + 2];
        sn[0][t] = ws[OFF_NRM + j * 3];    sn[1][t] = ws[OFF_NRM + j * 3 + 1]; sn[2][t] = ws[OFF_NRM + j * 3 + 2];
        ssc[t]   = ws[OFF_SC + j];
    }
    __syncthreads();

    const float pix = ws[OFF_P9 + i * 3], piy = ws[OFF_P9 + i * 3 + 1], piz = ws[OFF_P9 + i * 3 + 2];
    const float nix = ws[OFF_NRM + i * 3], niy = ws[OFF_NRM + i * 3 + 1], niz = ws[OFF_NRM + i * 3 + 2];
    const float ux = ws[OFF_UV + i * 6],     uy = ws[OFF_UV + i * 6 + 1], uz = ws[OFF_UV + i * 6 + 2];
    const float vx = ws[OFF_UV + i * 6 + 3], vy = ws[OFF_UV + i * 6 + 4], vz = ws[OFF_UV + i * 6 + 5];

    float ov0 = 0.f, ov1 = 0.f;
#pragma unroll 4
    for (int t = 0; t < 128; t++) {
        int j = sub * 128 + t;
        float dx = sp[0][j] - pix, dy = sp[1][j] - piy, dz = sp[2][j] - piz;
        float d2 = dx * dx + dy * dy + dz * dz;
        float cs = nix * sn[0][j] + niy * sn[1][j] + niz * sn[2][j];
        float tt = 2.f - cs;
        float w  = __expf(-d2 * tt * tt) * ssc[j];
        ov0 += w * (ux * dx + uy * dy + uz * dz);
        ov1 += w * (vx * dx + vy * dy + vz * dz);
    }
    red[tid][0] = ov0; red[tid][1] = ov1;
    __syncthreads();
    if (sub == 0) {
        float a = ov0 + red[64 + il][0] + red[128 + il][0] + red[192 + il][0];
        float b = ov1 + red[64 + il][1] + red[128 + il][1] + red[192 + il][1];
        atomicAdd(&ws[OFF_OV + i * 2],     a);
        atomicAdd(&ws[OFF_OV + i * 2 + 1], b);
    }
}

// ---------------- K3: finalize nuv + group_norm(h) ----------------
__global__ __launch_bounds__(256) void k_fin(float* __restrict__ ws, fp gng, fp gnb)
{
    const int i = blockIdx.x * 256 + threadIdx.x;

    float o0 = ws[OFF_OV + i * 2]     + 1e-5f;
    float o1 = ws[OFF_OV + i * 2 + 1] + 1e-5f;
    float nr = fmaxf(sqrtf(o0 * o0 + o1 * o1), 1e-12f);
    float ex = o0 / nr, ey = o1 / nr;

    const float ux = ws[OFF_UV + i * 6],     uy = ws[OFF_UV + i * 6 + 1], uz = ws[OFF_UV + i * 6 + 2];
    const float vx = ws[OFF_UV + i * 6 + 3], vy = ws[OFF_UV + i * 6 + 4], vz = ws[OFF_UV + i * 6 + 5];
    const float nx = ws[OFF_NRM + i * 3], ny = ws[OFF_NRM + i * 3 + 1], nz = ws[OFF_NRM + i * 3 + 2];

    ws[OFF_NUV + i * 9 + 0] = nx;
    ws[OFF_NUV + i * 9 + 1] = ny;
    ws[OFF_NUV + i * 9 + 2] = nz;
    ws[OFF_NUV + i * 9 + 3] =  ex * ux + ey * vx;
    ws[OFF_NUV + i * 9 + 4] =  ex * uy + ey * vy;
    ws[OFF_NUV + i * 9 + 5] =  ex * uz + ey * vz;
    ws[OFF_NUV + i * 9 + 6] = -ey * ux + ex * vx;
    ws[OFF_NUV + i * 9 + 7] = -ey * uy + ex * vy;
    ws[OFF_NUV + i * 9 + 8] = -ey * uz + ex * vz;

    const float invM = 1.f / (4.f * NP);
#pragma unroll
    for (int c = 0; c < 16; c++) {
        int g = c >> 2;
        float m   = ws[OFF_ACC + g] * invM;
        float var = ws[OFF_ACC + 4 + g] * invM - m * m;
        float inv = rsqrtf(var + 1e-5f);
        ws[OFF_HNRM + i * 16 + c] =
            (ws[OFF_HPRE + i * 16 + c] - m) * inv * gng[c] + gnb[c];
    }
}

// ---------------- K4: main conv — 16x16x32 MFMA + packed-f16 stage-2 ----------------
// grid = 64 i-blocks x 16 j-chunks, 4 waves; wave handles 16 i's.
// Per (i, 64-j group): lane = local j computes geometry, g, window w; packs
// w*g into 4 half2 and (w,0) once. Per 16-pair tile tau: A-frag gathered with
// 5 int bpermutes (quad0 rows = w*g, quad1 k=8 slot = w); B-frags hold A2
// (k=0..7) and b2 (k=8) so C_t = w*(A2 g + b2). Stage-2 packed: cvt_pkrtz
// pairs (C_2q,C_2q+1), pk_max relu, fdot2 against h-pairs from LDS (rows
// stride 48B -> 2-way bank aliasing, free). w folded into A; no AGPR
// round-trips (unified RF).
__global__ __launch_bounds__(256, 2) void k_conv(
    const float* __restrict__ ws,
    const float* __restrict__ cva1, const float* __restrict__ cvb1,
    const float* __restrict__ A2,   const float* __restrict__ B2,
    float* __restrict__ conv)
{
    __shared__ float4 sP[JCH];
    __shared__ float4 sN[JCH];
    __shared__ __align__(16) unsigned int sH2[JCH * HR];  // half2-packed h rows

    const int tid  = threadIdx.x;
    const int ib   = blockIdx.x >> 4;
    const int jc   = blockIdx.x & 15;
    const int j0   = jc * JCH;
    const int lane = tid & 63;
    const int wv   = tid >> 6;
    const int o    = lane & 15;
    const int quad = lane >> 4;
    const float IVS2 = 0.70710678118654752f;

    // stage the j-chunk (one j per thread)
    {
        const int t = tid;
        const int j = j0 + t;
        sP[t] = make_float4(ws[OFF_P9 + j * 3] * IVS2,
                            ws[OFF_P9 + j * 3 + 1] * IVS2,
                            ws[OFF_P9 + j * 3 + 2] * IVS2, 0.f);
        sN[t] = make_float4(ws[OFF_NRM + j * 3],
                            ws[OFF_NRM + j * 3 + 1],
                            ws[OFF_NRM + j * 3 + 2], 0.f);
        const float4* hs = (const float4*)(ws + OFF_HNRM + j * 16);
        float4 h0 = hs[0], h1 = hs[1], h2 = hs[2], h3 = hs[3];
        uint4 w0, w1;
        w0.x = pkrtz(h0.x, h0.y); w0.y = pkrtz(h0.z, h0.w);
        w0.z = pkrtz(h1.x, h1.y); w0.w = pkrtz(h1.z, h1.w);
        w1.x = pkrtz(h2.x, h2.y); w1.y = pkrtz(h2.z, h2.w);
        w1.z = pkrtz(h3.x, h3.y); w1.w = pkrtz(h3.z, h3.w);
        *(uint4*)(sH2 + t * HR)     = w0;
        *(uint4*)(sH2 + t * HR + 4) = w1;
    }

    const half8 h8z = (half8)(_Float16)0.f;

    // B-frags: quad0 lanes = A2 rows (k=0..7=c); quad1 lanes elem0 (k=8) = b2
    half8 Bf[16];
#pragma unroll
    for (int t = 0; t < 16; t++) {
        half8 v = h8z;
        if (lane < 16) {
            const float* row = A2 + (o * 16 + t) * 8;
#pragma unroll
            for (int c = 0; c < 8; c++) v[c] = (_Float16)row[c];
        } else if (lane < 32) {
            v[0] = (_Float16)B2[o * 16 + t];
        }
        Bf[t] = v;
    }

    float a1[24], b1c[8];
#pragma unroll
    for (int k = 0; k < 24; k++) a1[k] = cva1[k];
#pragma unroll
    for (int k = 0; k < 8; k++)  b1c[k] = cvb1[k];

    __syncthreads();

    const f32x4 zc = {0.f, 0.f, 0.f, 0.f};
    const fp16x2 h2z = {(__fp16)0.f, (__fp16)0.f};

#pragma unroll 1
    for (int ii = 0; ii < 16; ii++) {
        const int i = ib * 64 + wv * 16 + ii;     // wave-uniform -> s_loads
        const float pix = ws[OFF_P9 + i * 3 + 0] * IVS2;
        const float piy = ws[OFF_P9 + i * 3 + 1] * IVS2;
        const float piz = ws[OFF_P9 + i * 3 + 2] * IVS2;
        float r[9];
#pragma unroll
        for (int k = 0; k < 9; k++) r[k] = ws[OFF_NUV + i * 9 + k];

        float accO = 0.f;

#pragma unroll 1
        for (int jg = 0; jg < 4; jg++) {
            // geometry + g for 64 distinct j's (lane = local j)
            const int jl = jg * 64 + lane;
            const float4 pj = sP[jl];
            const float4 nj = sN[jl];
            const float dx = pj.x - pix, dy = pj.y - piy, dz = pj.z - piz;
            const float d2 = dx * dx + dy * dy + dz * dz;
            const float cs = r[0] * nj.x + r[1] * nj.y + r[2] * nj.z;
            const float tt = 2.f - cs;
            const float wwin = __expf(-d2 * tt * tt);
            const float X0 = r[0] * dx + r[1] * dy + r[2] * dz;
            const float X1 = r[3] * dx + r[4] * dy + r[5] * dz;
            const float X2 = r[6] * dx + r[7] * dy + r[8] * dz;
            float g[8];
#pragma unroll
            for (int c = 0; c < 8; c++)
                g[c] = fmaxf(a1[c * 3] * X0 + a1[c * 3 + 1] * X1 +
                             a1[c * 3 + 2] * X2 + b1c[c], 0.f);
            // pack w*g (4 half2) + (w,0) once per 64-j group
            unsigned int wg0 = pkrtz(wwin * g[0], wwin * g[1]);
            unsigned int wg1 = pkrtz(wwin * g[2], wwin * g[3]);
            unsigned int wg2 = pkrtz(wwin * g[4], wwin * g[5]);
            unsigned int wg3 = pkrtz(wwin * g[6], wwin * g[7]);
            unsigned int whp = pkrtz(wwin, 0.f);

#pragma unroll 1
            for (int tau = 0; tau < 4; tau++) {
                const int src = tau * 16 + o;
                unsigned int a0  = (unsigned int)__shfl((int)wg0, src, 64);
                unsigned int a1i = (unsigned int)__shfl((int)wg1, src, 64);
                unsigned int a2i = (unsigned int)__shfl((int)wg2, src, 64);
                unsigned int a3i = (unsigned int)__shfl((int)wg3, src, 64);
                unsigned int aw  = (unsigned int)__shfl((int)whp, src, 64);
                uint4 av;
                av.x = (quad == 0) ? a0 : ((quad == 1) ? aw : 0u);
                av.y = (quad == 0) ? a1i : 0u;
                av.z = (quad == 0) ? a2i : 0u;
                av.w = (quad == 0) ? a3i : 0u;
                half8 Af; __builtin_memcpy(&Af, &av, 16);

                // MFMAs + packed relu
                fp16x2 P[32];
#pragma unroll
                for (int q = 0; q < 8; q++) {
                    f32x4 C0 = __builtin_amdgcn_mfma_f32_16x16x32_f16(Af, Bf[2 * q],     zc, 0, 0, 0);
                    f32x4 C1 = __builtin_amdgcn_mfma_f32_16x16x32_f16(Af, Bf[2 * q + 1], zc, 0, 0, 0);
#pragma unroll
                    for (int r2 = 0; r2 < 4; r2++) {
                        fp16x2 pp = __builtin_amdgcn_cvt_pkrtz(C0[r2], C1[r2]);
                        P[r2 * 8 + q] = __builtin_elementwise_max(pp, h2z);
                    }
                }

                // packed h-contraction
#pragma unroll
                for (int r2 = 0; r2 < 4; r2++) {
                    const unsigned int* hr = sH2 + (jg * 64 + tau * 16 + quad * 4 + r2) * HR;
                    const uint4 ha = *(const uint4*)hr;
                    const uint4 hb = *(const uint4*)(hr + 4);
                    accO = __builtin_amdgcn_fdot2(P[r2 * 8 + 0], u2h(ha.x), accO, false);
                    accO = __builtin_amdgcn_fdot2(P[r2 * 8 + 1], u2h(ha.y), accO, false);
                    accO = __builtin_amdgcn_fdot2(P[r2 * 8 + 2], u2h(ha.z), accO, false);
                    accO = __builtin_amdgcn_fdot2(P[r2 * 8 + 3], u2h(ha.w), accO, false);
                    accO = __builtin_amdgcn_fdot2(P[r2 * 8 + 4], u2h(hb.x), accO, false);
                    accO = __builtin_amdgcn_fdot2(P[r2 * 8 + 5], u2h(hb.y), accO, false);
                    accO = __builtin_amdgcn_fdot2(P[r2 * 8 + 6], u2h(hb.z), accO, false);
                    accO = __builtin_amdgcn_fdot2(P[r2 * 8 + 7], u2h(hb.w), accO, false);
                }
            }
        }

        accO += __shfl_xor(accO, 16, 64);
        accO += __shfl_xor(accO, 32, 64);
        if (lane < 16) atomicAdd(&conv[i * 16 + o], accO);
    }
}

// ---------------- K5: output MLP + group sums ----------------
__global__ __launch_bounds__(256) void k_post1(
    float* __restrict__ ws, fp now1, fp nob1, fp now2, fp nob2)
{
    const int i = blockIdx.x * 256 + threadIdx.x;
    float cv[16];
#pragma unroll
    for (int o = 0; o < 16; o++) cv[o] = ws[OFF_CONV + i * 16 + o];

    float y1[16];
#pragma unroll
    for (int u = 0; u < 16; u++) {
        float a = nob1[u];
#pragma unroll
        for (int k = 0; k < 16; k++) a += now1[u * 16 + k] * cv[k];
        y1[u] = lk(a);
    }
    float y2[16];
#pragma unroll
    for (int u = 0; u < 16; u++) {
        float a = nob2[u];
#pragma unroll
        for (int k = 0; k < 16; k++) a += now2[u * 16 + k] * y1[k];
        y2[u] = lk(a);
        ws[OFF_Y2 + i * 16 + u] = y2[u];
    }
#pragma unroll
    for (int g = 0; g < 4; g++) {
        float s = 0.f, ss = 0.f;
#pragma unroll
        for (int k = 0; k < 4; k++) { float v = y2[g * 4 + k]; s += v; ss += v * v; }
#pragma unroll
        for (int off = 32; off > 0; off >>= 1) {
            s  += __shfl_down(s,  off);
            ss += __shfl_down(ss, off);
        }
        if ((threadIdx.x & 63) == 0) {
            atomicAdd(&ws[OFF_ACC + 8 + g],  s);
            atomicAdd(&ws[OFF_ACC + 12 + g], ss);
        }
    }
}

// ---------------- K6: group_norm(y) + site MLP + linear transform + sum ----------------
__global__ __launch_bounds__(256) void k_post2(
    const float* __restrict__ ws, fp feats, fp gg, fp gb,
    fp llw1, fp llb1, fp llw2, fp llb2, fp ltw, fp ltb,
    float* __restrict__ out)
{
    const int i = blockIdx.x * 256 + threadIdx.x;
    const float invM = 1.f / (4.f * NP);

    float z[16];
#pragma unroll
    for (int c = 0; c < 16; c++) {
        int g = c >> 2;
        float m   = ws[OFF_ACC + 8 + g] * invM;
        float var = ws[OFF_ACC + 12 + g] * invM - m * m;
        float inv = rsqrtf(var + 1e-5f);
        z[c] = (ws[OFF_Y2 + i * 16 + c] - m) * inv * gg[c] + gb[c];
    }
    float r1[16];
#pragma unroll
    for (int o = 0; o < 16; o++) {
        float a = llb1[o];
#pragma unroll
        for (int k = 0; k < 16; k++) a += llw1[o * 16 + k] * z[k];
        r1[o] = fmaxf(a, 0.f);
    }
    float f[16];
#pragma unroll
    for (int c = 0; c < 16; c++) f[c] = feats[i * 16 + c];
#pragma unroll
    for (int o = 0; o < 16; o++) {
        float a = llb2[o];
#pragma unroll
        for (int k = 0; k < 16; k++) a += llw2[o * 16 + k] * r1[k];
        float x = ltb[o];
#pragma unroll
        for (int k = 0; k < 16; k++) x += ltw[o * 16 + k] * f[k];
        out[i * 16 + o] = x + a;
    }
}

extern "C" void kernel_launch(void* const* d_in, const int* in_sizes, int n_in,
                              void* d_out, int out_size, void* d_ws, size_t ws_size,
                              hipStream_t stream)
{
    fp xyz  = (fp)d_in[0];
    fp nrm  = (fp)d_in[1];
    fp fts  = (fp)d_in[2];
    fp osw1 = (fp)d_in[3],  osb1 = (fp)d_in[4],  osw2 = (fp)d_in[5],  osb2 = (fp)d_in[6];
    fp niw1 = (fp)d_in[7],  nib1 = (fp)d_in[8],  niw2 = (fp)d_in[9],  nib2 = (fp)d_in[10];
    fp gng  = (fp)d_in[11], gnb  = (fp)d_in[12];
    fp cva1 = (fp)d_in[13], cvb1 = (fp)d_in[14], cva2 = (fp)d_in[15], cvb2 = (fp)d_in[16];
    fp now1 = (fp)d_in[17], nob1 = (fp)d_in[18], now2 = (fp)d_in[19], nob2 = (fp)d_in[20];
    fp gog  = (fp)d_in[21], gob  = (fp)d_in[22];
    fp llw1 = (fp)d_in[23], llb1 = (fp)d_in[24], llw2 = (fp)d_in[25], llb2 = (fp)d_in[26];
    fp ltw  = (fp)d_in[27], ltb  = (fp)d_in[28];

    float* ws = (float*)d_ws;

    (void)hipMemsetAsync(d_ws, 0, (size_t)ZERO_FLTS * sizeof(float), stream);
    k_prep<<<NP / 256, 256, 0, stream>>>(xyz, nrm, fts,
                                         osw1, osb1, osw2, osb2,
                                         niw1, nib1, niw2, nib2, ws);
    k_mesh<<<512, 256, 0, stream>>>(ws);
    k_fin<<<NP / 256, 256, 0, stream>>>(ws, gng, gnb);
    k_conv<<<64 * NJC, 256, 0, stream>>>(ws, cva1, cvb1, cva2, cvb2, ws + OFF_CONV);
    k_post1<<<NP / 256, 256, 0, stream>>>(ws, now1, nob1, now2, nob2);
    k_post2<<<NP / 256, 256, 0, stream>>>(ws, fts, gog, gob,
                                          llw1, llb1, llw2, llb2, ltw, ltb,
                                          (float*)d_out);
}

// Round 8
// 473.559 us; speedup vs baseline: 4.4572x; 1.1215x over previous
//
#include <hip/hip_runtime.h>

#define NP 4096          // number of points (fixed by problem)
#define NJC 32           // j-chunks for the main conv
#define JCH (NP / NJC)   // 128 j's per conv workgroup
#define HR  12           // sH2 row stride in 32-bit words (48B): 16B-aligned, 2-way banks

typedef const float* fp;

using half4  = __attribute__((ext_vector_type(4))) __fp16;     // K=16 MFMA frag
using fp16x2 = __attribute__((ext_vector_type(2))) __fp16;     // pkrtz/fdot2 type
using f32x4  = __attribute__((ext_vector_type(4))) float;

__device__ __forceinline__ float lk(float x) { return x >= 0.f ? x : 0.2f * x; }

__device__ __forceinline__ unsigned int pkrtz(float a, float b) {
    fp16x2 h = __builtin_amdgcn_cvt_pkrtz(a, b);
    unsigned int u; __builtin_memcpy(&u, &h, 4); return u;
}
__device__ __forceinline__ fp16x2 u2h(unsigned int u) {
    fp16x2 h; __builtin_memcpy(&h, &u, 4); return h;
}
__device__ __forceinline__ fp16x2 pkmax0(fp16x2 a, fp16x2 z) {
    fp16x2 d;
    asm("v_pk_max_f16 %0, %1, %2" : "=v"(d) : "v"(a), "v"(z));
    return d;
}

// ---- workspace layout (float offsets) ----
// zeroed region (memset each launch):
#define OFF_ACC   0                       // [0..7] gsum/gssq in, [8..15] gsum/gssq out
#define OFF_OV    16                      // 2*NP  load_mesh ov accumulator
#define OFF_CONV  (16 + 2*NP)             // 16*NP conv output accumulator
#define ZERO_FLTS (16 + 2*NP + 16*NP)
// plain scratch:
#define OFF_SC    ZERO_FLTS               // NP     scores
#define OFF_UV    (OFF_SC  + NP)          // 6*NP   tangent vectors u,v
#define OFF_P9    (OFF_UV  + 6*NP)        // 3*NP   xyz / RADIUS
#define OFF_NRM   (OFF_P9  + 3*NP)        // 3*NP   normals fp32
#define OFF_HPRE  (OFF_NRM + 3*NP)        // 16*NP  h before group_norm
#define OFF_HNRM  (OFF_HPRE+ 16*NP)       // 16*NP  h after group_norm (16B-aligned)
#define OFF_NUV   (OFF_HNRM+ 16*NP)       // 9*NP   nuv frames
#define OFF_Y2    (OFF_NUV + 9*NP)        // 16*NP  y after output MLP (pre group_norm)
#define WS_FLTS   (OFF_Y2  + 16*NP)

// ---------------- K1: per-point prep ----------------
__global__ __launch_bounds__(256) void k_prep(
    fp xyz, fp nrm, fp feats,
    fp osw1, fp osb1, fp osw2, fp osb2,
    fp niw1, fp nib1, fp niw2, fp nib2,
    float* __restrict__ ws)
{
    const int i = blockIdx.x * 256 + threadIdx.x;

    float f[16];
#pragma unroll
    for (int c = 0; c < 16; c++) f[c] = feats[i * 16 + c];

    float sc = osb2[0];
#pragma unroll
    for (int u = 0; u < 16; u++) {
        float a = osb1[u];
#pragma unroll
        for (int c = 0; c < 16; c++) a += osw1[u * 16 + c] * f[c];
        sc += osw2[u] * lk(a);
    }
    ws[OFF_SC + i] = sc;

    float h1[16];
#pragma unroll
    for (int u = 0; u < 16; u++) {
        float a = nib1[u];
#pragma unroll
        for (int c = 0; c < 16; c++) a += niw1[u * 16 + c] * f[c];
        h1[u] = lk(a);
    }
    float h2[16];
#pragma unroll
    for (int u = 0; u < 16; u++) {
        float a = nib2[u];
#pragma unroll
        for (int c = 0; c < 16; c++) a += niw2[u * 16 + c] * h1[c];
        h2[u] = lk(a);
        ws[OFF_HPRE + i * 16 + u] = h2[u];
    }

#pragma unroll
    for (int g = 0; g < 4; g++) {
        float s = 0.f, ss = 0.f;
#pragma unroll
        for (int k = 0; k < 4; k++) { float v = h2[g * 4 + k]; s += v; ss += v * v; }
#pragma unroll
        for (int off = 32; off > 0; off >>= 1) {
            s  += __shfl_down(s,  off);
            ss += __shfl_down(ss, off);
        }
        if ((threadIdx.x & 63) == 0) {
            atomicAdd(&ws[OFF_ACC + g],     s);
            atomicAdd(&ws[OFF_ACC + 4 + g], ss);
        }
    }

    float nx = nrm[i * 3], ny = nrm[i * 3 + 1], nz = nrm[i * 3 + 2];
    float s  = (nz >= 0.f) ? 1.f : -1.f;
    float a  = -1.f / (s + nz);
    float b  = nx * ny * a;
    float ux = 1.f + s * nx * nx * a, uy = s * b,            uz = -s * nx;
    float vx = b,                     vy = s + ny * ny * a,  vz = -ny;
    ws[OFF_UV + i * 6 + 0] = ux; ws[OFF_UV + i * 6 + 1] = uy; ws[OFF_UV + i * 6 + 2] = uz;
    ws[OFF_UV + i * 6 + 3] = vx; ws[OFF_UV + i * 6 + 4] = vy; ws[OFF_UV + i * 6 + 5] = vz;
    const float IR = 1.f / 9.f;
    ws[OFF_P9 + i * 3 + 0] = xyz[i * 3 + 0] * IR;
    ws[OFF_P9 + i * 3 + 1] = xyz[i * 3 + 1] * IR;
    ws[OFF_P9 + i * 3 + 2] = xyz[i * 3 + 2] * IR;
    ws[OFF_NRM + i * 3 + 0] = nx;
    ws[OFF_NRM + i * 3 + 1] = ny;
    ws[OFF_NRM + i * 3 + 2] = nz;
}

// ---------------- K2: load_mesh O(N^2) pair sum ----------------
__global__ __launch_bounds__(256) void k_mesh(float* __restrict__ ws)
{
    __shared__ float sp[3][512];
    __shared__ float sn[3][512];
    __shared__ float ssc[512];
    __shared__ float red[256][2];

    const int tid = threadIdx.x;
    const int ib = blockIdx.x >> 3, jc = blockIdx.x & 7;
    const int il = tid & 63, sub = tid >> 6;
    const int i = ib * 64 + il;
    const int j0 = jc * 512;

    for (int t = tid; t < 512; t += 256) {
        int j = j0 + t;
        sp[0][t] = ws[OFF_P9 + j * 3];     sp[1][t] = ws[OFF_P9 + j * 3 + 1];  sp[2][t] = ws[OFF_P9 + j * 3 + 2];
        sn[0][t] = ws[OFF_NRM + j * 3];    sn[1][t] = ws[OFF_NRM + j * 3 + 1]; sn[2][t] = ws[OFF_NRM + j * 3 + 2];
        ssc[t]   = ws[OFF_SC + j];
    }
    __syncthreads();

    const float pix = ws[OFF_P9 + i * 3], piy = ws[OFF_P9 + i * 3 + 1], piz = ws[OFF_P9 + i * 3 + 2];
    const float nix = ws[OFF_NRM + i * 3], niy = ws[OFF_NRM + i * 3 + 1], niz = ws[OFF_NRM + i * 3 + 2];
    const float ux = ws[OFF_UV + i * 6],     uy = ws[OFF_UV + i * 6 + 1], uz = ws[OFF_UV + i * 6 + 2];
    const float vx = ws[OFF_UV + i * 6 + 3], vy = ws[OFF_UV + i * 6 + 4], vz = ws[OFF_UV + i * 6 + 5];

    float ov0 = 0.f, ov1 = 0.f;
#pragma unroll 4
    for (int t = 0; t < 128; t++) {
        int j = sub * 128 + t;
        float dx = sp[0][j] - pix, dy = sp[1][j] - piy, dz = sp[2][j] - piz;
        float d2 = dx * dx + dy * dy + dz * dz;
        float cs = nix * sn[0][j] + niy * sn[1][j] + niz * sn[2][j];
        float tt = 2.f - cs;
        float w  = __expf(-d2 * tt * tt) * ssc[j];
        ov0 += w * (ux * dx + uy * dy + uz * dz);
        ov1 += w * (vx * dx + vy * dy + vz * dz);
    }
    red[tid][0] = ov0; red[tid][1] = ov1;
    __syncthreads();
    if (sub == 0) {
        float a = ov0 + red[64 + il][0] + red[128 + il][0] + red[192 + il][0];
        float b = ov1 + red[64 + il][1] + red[128 + il][1] + red[192 + il][1];
        atomicAdd(&ws[OFF_OV + i * 2],     a);
        atomicAdd(&ws[OFF_OV + i * 2 + 1], b);
    }
}

// ---------------- K3: finalize nuv + group_norm(h) ----------------
__global__ __launch_bounds__(256) void k_fin(float* __restrict__ ws, fp gng, fp gnb)
{
    const int i = blockIdx.x * 256 + threadIdx.x;

    float o0 = ws[OFF_OV + i * 2]     + 1e-5f;
    float o1 = ws[OFF_OV + i * 2 + 1] + 1e-5f;
    float nr = fmaxf(sqrtf(o0 * o0 + o1 * o1), 1e-12f);
    float ex = o0 / nr, ey = o1 / nr;

    const float ux = ws[OFF_UV + i * 6],     uy = ws[OFF_UV + i * 6 + 1], uz = ws[OFF_UV + i * 6 + 2];
    const float vx = ws[OFF_UV + i * 6 + 3], vy = ws[OFF_UV + i * 6 + 4], vz = ws[OFF_UV + i * 6 + 5];
    const float nx = ws[OFF_NRM + i * 3], ny = ws[OFF_NRM + i * 3 + 1], nz = ws[OFF_NRM + i * 3 + 2];

    ws[OFF_NUV + i * 9 + 0] = nx;
    ws[OFF_NUV + i * 9 + 1] = ny;
    ws[OFF_NUV + i * 9 + 2] = nz;
    ws[OFF_NUV + i * 9 + 3] =  ex * ux + ey * vx;
    ws[OFF_NUV + i * 9 + 4] =  ex * uy + ey * vy;
    ws[OFF_NUV + i * 9 + 5] =  ex * uz + ey * vz;
    ws[OFF_NUV + i * 9 + 6] = -ey * ux + ex * vx;
    ws[OFF_NUV + i * 9 + 7] = -ey * uy + ex * vy;
    ws[OFF_NUV + i * 9 + 8] = -ey * uz + ex * vz;

    const float invM = 1.f / (4.f * NP);
#pragma unroll
    for (int c = 0; c < 16; c++) {
        int g = c >> 2;
        float m   = ws[OFF_ACC + g] * invM;
        float var = ws[OFF_ACC + 4 + g] * invM - m * m;
        float inv = rsqrtf(var + 1e-5f);
        ws[OFF_HNRM + i * 16 + c] =
            (ws[OFF_HPRE + i * 16 + c] - m) * inv * gng[c] + gnb[c];
    }
}

// ---------------- K4: main conv — 16x16x16 MFMA (K=16, 2-reg frags) ----------------
// grid = 64 i-blocks x 32 j-chunks, 4 waves; wave handles 16 i's, 128 j's.
// K=16 legacy MFMA: lane holds k=quad*4+j. A rows = pairs: quad0 k0-3 = w*g[0..3],
// quad1 k4-7 = w*g[4..7], quad2 k8 = w (bias slot), rest 0. B cols = o per t:
// quad0/1 = A2 halves, quad2 k8 = b2. C layout: col=lane&15=o, row=quad*4+reg.
// Stage-2 in two q-halves (P[16] regs): cvt_pkrtz pair, v_pk_max_f16 relu,
// v_dot2_f32_f16 vs half2 h rows in LDS (stride 48B, 2-way banks = free).
// Register budget deliberately < 128 VGPR so nothing lands in AGPRs
// (round 7: Bf[16] K=32 frags -> AGPR bounce, 2.6x hidden VALU).
__global__ __launch_bounds__(256, 4) void k_conv(
    const float* __restrict__ ws,
    const float* __restrict__ cva1, const float* __restrict__ cvb1,
    const float* __restrict__ A2,   const float* __restrict__ B2,
    float* __restrict__ conv)
{
    __shared__ float4 sP[JCH];
    __shared__ float4 sN[JCH];
    __shared__ __align__(16) unsigned int sH2[JCH * HR];  // half2-packed h rows

    const int tid  = threadIdx.x;
    const int ib   = blockIdx.x >> 5;     // NJC == 32
    const int jc   = blockIdx.x & 31;
    const int j0   = jc * JCH;
    const int lane = tid & 63;
    const int wv   = tid >> 6;
    const int o    = lane & 15;
    const int quad = lane >> 4;
    const float IVS2 = 0.70710678118654752f;

    // stage the j-chunk (one j per thread, first JCH threads)
    if (tid < JCH) {
        const int t = tid;
        const int j = j0 + t;
        sP[t] = make_float4(ws[OFF_P9 + j * 3] * IVS2,
                            ws[OFF_P9 + j * 3 + 1] * IVS2,
                            ws[OFF_P9 + j * 3 + 2] * IVS2, 0.f);
        sN[t] = make_float4(ws[OFF_NRM + j * 3],
                            ws[OFF_NRM + j * 3 + 1],
                            ws[OFF_NRM + j * 3 + 2], 0.f);
        const float4* hs = (const float4*)(ws + OFF_HNRM + j * 16);
        float4 h0 = hs[0], h1 = hs[1], h2 = hs[2], h3 = hs[3];
        uint4 w0, w1;
        w0.x = pkrtz(h0.x, h0.y); w0.y = pkrtz(h0.z, h0.w);
        w0.z = pkrtz(h1.x, h1.y); w0.w = pkrtz(h1.z, h1.w);
        w1.x = pkrtz(h2.x, h2.y); w1.y = pkrtz(h2.z, h2.w);
        w1.z = pkrtz(h3.x, h3.y); w1.w = pkrtz(h3.z, h3.w);
        *(uint4*)(sH2 + t * HR)     = w0;
        *(uint4*)(sH2 + t * HR + 4) = w1;
    }

    // B-frags (K=16): 2 regs each. quad0: A2[o,t][0..3]; quad1: A2[o,t][4..7];
    // quad2: (b2, 0, 0, 0); quad3: 0.
    half4 Bf[16];
#pragma unroll
    for (int t = 0; t < 16; t++) {
        half4 v = {(__fp16)0.f, (__fp16)0.f, (__fp16)0.f, (__fp16)0.f};
        const float* row = A2 + (o * 16 + t) * 8;
        if (quad == 0) {
#pragma unroll
            for (int c = 0; c < 4; c++) v[c] = (__fp16)row[c];
        } else if (quad == 1) {
#pragma unroll
            for (int c = 0; c < 4; c++) v[c] = (__fp16)row[4 + c];
        } else if (quad == 2) {
            v[0] = (__fp16)B2[o * 16 + t];
        }
        Bf[t] = v;
    }

    float a1[24], b1c[8];
#pragma unroll
    for (int k = 0; k < 24; k++) a1[k] = cva1[k];
#pragma unroll
    for (int k = 0; k < 8; k++)  b1c[k] = cvb1[k];

    __syncthreads();

    const f32x4 zc = {0.f, 0.f, 0.f, 0.f};
    const fp16x2 h2z = {(__fp16)0.f, (__fp16)0.f};
    const int o4 = o << 2;

#pragma unroll 1
    for (int ii = 0; ii < 16; ii++) {
        const int i = ib * 64 + wv * 16 + ii;     // wave-uniform -> s_loads
        const float pix = ws[OFF_P9 + i * 3 + 0] * IVS2;
        const float piy = ws[OFF_P9 + i * 3 + 1] * IVS2;
        const float piz = ws[OFF_P9 + i * 3 + 2] * IVS2;
        float r[9];
#pragma unroll
        for (int k = 0; k < 9; k++) r[k] = ws[OFF_NUV + i * 9 + k];

        float accO = 0.f;

#pragma unroll 1
        for (int jg = 0; jg < JCH / 64; jg++) {
            // geometry + g for 64 distinct j's (lane = local j)
            const int jl = jg * 64 + lane;
            const float4 pj = sP[jl];
            const float4 nj = sN[jl];
            const float dx = pj.x - pix, dy = pj.y - piy, dz = pj.z - piz;
            const float d2 = dx * dx + dy * dy + dz * dz;
            const float cs = r[0] * nj.x + r[1] * nj.y + r[2] * nj.z;
            const float tt = 2.f - cs;
            const float wwin = __expf(-d2 * tt * tt);
            const float X0 = r[0] * dx + r[1] * dy + r[2] * dz;
            const float X1 = r[3] * dx + r[4] * dy + r[5] * dz;
            const float X2 = r[6] * dx + r[7] * dy + r[8] * dz;
            float g[8];
#pragma unroll
            for (int c = 0; c < 8; c++)
                g[c] = fmaxf(a1[c * 3] * X0 + a1[c * 3 + 1] * X1 +
                             a1[c * 3 + 2] * X2 + b1c[c], 0.f);
            // pack w*g (4 half2) + (w,0) once per 64-j group
            const int wg0 = (int)pkrtz(wwin * g[0], wwin * g[1]);
            const int wg1 = (int)pkrtz(wwin * g[2], wwin * g[3]);
            const int wg2 = (int)pkrtz(wwin * g[4], wwin * g[5]);
            const int wg3 = (int)pkrtz(wwin * g[6], wwin * g[7]);
            const int whp = (int)pkrtz(wwin, 0.f);

#pragma unroll 1
            for (int tau = 0; tau < 4; tau++) {
                const int srcb = tau * 64 + o4;   // source lane byte addr
                const unsigned u0 = (unsigned)__builtin_amdgcn_ds_bpermute(srcb, wg0);
                const unsigned u1 = (unsigned)__builtin_amdgcn_ds_bpermute(srcb, wg1);
                const unsigned u2 = (unsigned)__builtin_amdgcn_ds_bpermute(srcb, wg2);
                const unsigned u3 = (unsigned)__builtin_amdgcn_ds_bpermute(srcb, wg3);
                const unsigned uw = (unsigned)__builtin_amdgcn_ds_bpermute(srcb, whp);
                uint2 av;
                av.x = (quad == 0) ? u0 : (quad == 1) ? u2 : (quad == 2) ? uw : 0u;
                av.y = (quad == 0) ? u1 : (quad == 1) ? u3 : 0u;
                half4 Af; __builtin_memcpy(&Af, &av, 8);

#pragma unroll
                for (int hq = 0; hq < 2; hq++) {
                    fp16x2 P[16];
#pragma unroll
                    for (int q2 = 0; q2 < 4; q2++) {
                        const int q = hq * 4 + q2;
                        f32x4 C0 = __builtin_amdgcn_mfma_f32_16x16x16f16(Af, Bf[2 * q],     zc, 0, 0, 0);
                        f32x4 C1 = __builtin_amdgcn_mfma_f32_16x16x16f16(Af, Bf[2 * q + 1], zc, 0, 0, 0);
#pragma unroll
                        for (int r2 = 0; r2 < 4; r2++) {
                            fp16x2 pp = __builtin_amdgcn_cvt_pkrtz(C0[r2], C1[r2]);
                            P[r2 * 4 + q2] = pkmax0(pp, h2z);
                        }
                    }
#pragma unroll
                    for (int r2 = 0; r2 < 4; r2++) {
                        const unsigned int* hr =
                            sH2 + (jg * 64 + tau * 16 + quad * 4 + r2) * HR + hq * 4;
                        const uint4 ha = *(const uint4*)hr;
                        accO = __builtin_amdgcn_fdot2(P[r2 * 4 + 0], u2h(ha.x), accO, false);
                        accO = __builtin_amdgcn_fdot2(P[r2 * 4 + 1], u2h(ha.y), accO, false);
                        accO = __builtin_amdgcn_fdot2(P[r2 * 4 + 2], u2h(ha.z), accO, false);
                        accO = __builtin_amdgcn_fdot2(P[r2 * 4 + 3], u2h(ha.w), accO, false);
                    }
                }
            }
        }

        accO += __shfl_xor(accO, 16, 64);
        accO += __shfl_xor(accO, 32, 64);
        if (lane < 16) atomicAdd(&conv[i * 16 + o], accO);
    }
}

// ---------------- K5: output MLP + group sums ----------------
__global__ __launch_bounds__(256) void k_post1(
    float* __restrict__ ws, fp now1, fp nob1, fp now2, fp nob2)
{
    const int i = blockIdx.x * 256 + threadIdx.x;
    float cv[16];
#pragma unroll
    for (int o = 0; o < 16; o++) cv[o] = ws[OFF_CONV + i * 16 + o];

    float y1[16];
#pragma unroll
    for (int u = 0; u < 16; u++) {
        float a = nob1[u];
#pragma unroll
        for (int k = 0; k < 16; k++) a += now1[u * 16 + k] * cv[k];
        y1[u] = lk(a);
    }
    float y2[16];
#pragma unroll
    for (int u = 0; u < 16; u++) {
        float a = nob2[u];
#pragma unroll
        for (int k = 0; k < 16; k++) a += now2[u * 16 + k] * y1[k];
        y2[u] = lk(a);
        ws[OFF_Y2 + i * 16 + u] = y2[u];
    }
#pragma unroll
    for (int g = 0; g < 4; g++) {
        float s = 0.f, ss = 0.f;
#pragma unroll
        for (int k = 0; k < 4; k++) { float v = y2[g * 4 + k]; s += v; ss += v * v; }
#pragma unroll
        for (int off = 32; off > 0; off >>= 1) {
            s  += __shfl_down(s,  off);
            ss += __shfl_down(ss, off);
        }
        if ((threadIdx.x & 63) == 0) {
            atomicAdd(&ws[OFF_ACC + 8 + g],  s);
            atomicAdd(&ws[OFF_ACC + 12 + g], ss);
        }
    }
}

// ---------------- K6: group_norm(y) + site MLP + linear transform + sum ----------------
__global__ __launch_bounds__(256) void k_post2(
    const float* __restrict__ ws, fp feats, fp gg, fp gb,
    fp llw1, fp llb1, fp llw2, fp llb2, fp ltw, fp ltb,
    float* __restrict__ out)
{
    const int i = blockIdx.x * 256 + threadIdx.x;
    const float invM = 1.f / (4.f * NP);

    float z[16];
#pragma unroll
    for (int c = 0; c < 16; c++) {
        int g = c >> 2;
        float m   = ws[OFF_ACC + 8 + g] * invM;
        float var = ws[OFF_ACC + 12 + g] * invM - m * m;
        float inv = rsqrtf(var + 1e-5f);
        z[c] = (ws[OFF_Y2 + i * 16 + c] - m) * inv * gg[c] + gb[c];
    }
    float r1[16];
#pragma unroll
    for (int o = 0; o < 16; o++) {
        float a = llb1[o];
#pragma unroll
        for (int k = 0; k < 16; k++) a += llw1[o * 16 + k] * z[k];
        r1[o] = fmaxf(a, 0.f);
    }
    float f[16];
#pragma unroll
    for (int c = 0; c < 16; c++) f[c] = feats[i * 16 + c];
#pragma unroll
    for (int o = 0; o < 16; o++) {
        float a = llb2[o];
#pragma unroll
        for (int k = 0; k < 16; k++) a += llw2[o * 16 + k] * r1[k];
        float x = ltb[o];
#pragma unroll
        for (int k = 0; k < 16; k++) x += ltw[o * 16 + k] * f[k];
        out[i * 16 + o] = x + a;
    }
}

extern "C" void kernel_launch(void* const* d_in, const int* in_sizes, int n_in,
                              void* d_out, int out_size, void* d_ws, size_t ws_size,
                              hipStream_t stream)
{
    fp xyz  = (fp)d_in[0];
    fp nrm  = (fp)d_in[1];
    fp fts  = (fp)d_in[2];
    fp osw1 = (fp)d_in[3],  osb1 = (fp)d_in[4],  osw2 = (fp)d_in[5],  osb2 = (fp)d_in[6];
    fp niw1 = (fp)d_in[7],  nib1 = (fp)d_in[8],  niw2 = (fp)d_in[9],  nib2 = (fp)d_in[10];
    fp gng  = (fp)d_in[11], gnb  = (fp)d_in[12];
    fp cva1 = (fp)d_in[13], cvb1 = (fp)d_in[14], cva2 = (fp)d_in[15], cvb2 = (fp)d_in[16];
    fp now1 = (fp)d_in[17], nob1 = (fp)d_in[18], now2 = (fp)d_in[19], nob2 = (fp)d_in[20];
    fp gog  = (fp)d_in[21], gob  = (fp)d_in[22];
    fp llw1 = (fp)d_in[23], llb1 = (fp)d_in[24], llw2 = (fp)d_in[25], llb2 = (fp)d_in[26];
    fp ltw  = (fp)d_in[27], ltb  = (fp)d_in[28];

    float* ws = (float*)d_ws;

    (void)hipMemsetAsync(d_ws, 0, (size_t)ZERO_FLTS * sizeof(float), stream);
    k_prep<<<NP / 256, 256, 0, stream>>>(xyz, nrm, fts,
                                         osw1, osb1, osw2, osb2,
                                         niw1, nib1, niw2, nib2, ws);
    k_mesh<<<512, 256, 0, stream>>>(ws);
    k_fin<<<NP / 256, 256, 0, stream>>>(ws, gng, gnb);
    k_conv<<<64 * NJC, 256, 0, stream>>>(ws, cva1, cvb1, cva2, cvb2, ws + OFF_CONV);
    k_post1<<<NP / 256, 256, 0, stream>>>(ws, now1, nob1, now2, nob2);
    k_post2<<<NP / 256, 256, 0, stream>>>(ws, fts, gog, gob,
                                          llw1, llb1, llw2, llb2, ltw, ltb,
                                          (float*)d_out);
}